// Round 11
// baseline (262.371 us; speedup 1.0000x reference)
//
#include <hip/hip_runtime.h>
#include <stdint.h>

#define NG   32
#define NPG  512
#define EPG  4096
#define DN   128
#define DP   64
#define NN   (NG*NPG)          // 16384 nodes
#define NE   (NG*EPG)          // 131072 edges
#define KD   320               // in_dim
#define HD   768               // hidden
#define SEQ  (1+NPG+EPG)       // 4609
#define TOK_ELEMS ((size_t)NG*SEQ*HD)
#define MASK_ELEMS ((size_t)NG*SEQ)
#define NFRAG (12*10*4*64)     // 30720 16B fragments in Wb2

typedef unsigned short u16;
typedef __attribute__((ext_vector_type(8))) __bf16 bf16x8;
typedef __attribute__((ext_vector_type(8))) short  s16x8;
typedef __attribute__((ext_vector_type(4))) float  f32x4;

__device__ __forceinline__ u16 f2bf(float f) {
    uint32_t u = __builtin_bit_cast(uint32_t, f);
    u += 0x7fffu + ((u >> 16) & 1u);          // RNE
    return (u16)(u >> 16);
}

// ---------------- aux kernels ----------------
__global__ void ptr_k(const int* __restrict__ batch, const int* __restrict__ eidx,
                      int* __restrict__ nptr, int* __restrict__ eptr) {
    int t = threadIdx.x;
    if (t < NG) {
        int g = t, lo = 0, hi = NN;
        while (lo < hi) { int mid = (lo + hi) >> 1; if (batch[mid] < g) lo = mid + 1; else hi = mid; }
        nptr[g] = lo;
    } else if (t < 2 * NG) {
        int g = t - NG, lo = 0, hi = NE;
        while (lo < hi) { int mid = (lo + hi) >> 1; if (batch[eidx[mid]] < g) lo = mid + 1; else hi = mid; }
        eptr[g] = lo;
    }
}

// W [HD][KD] f32 -> Wb2 in MFMA-fragment order: fragment i = (nt,kt,ni,lane),
// 16B of bf16 = W[nt*64+ni*16+(lane&15)][kt*32+(lane>>4)*8 .. +8].
// A wave's 4 fragment loads per (nt,kt) are then 4x 1KB fully-coalesced
// contiguous global_load_dwordx4 served from L1/L2 -- no LDS needed.
__global__ void wconv_k(const float* __restrict__ W, u16* __restrict__ Wb2) {
    int i = blockIdx.x * 256 + threadIdx.x;
    if (i >= NFRAG) return;
    int nt = i / 2560, rem = i % 2560;
    int kt = rem / 256, rem2 = rem % 256;
    int ni = rem2 / 64, lane = rem2 & 63;
    int row = nt * 64 + ni * 16 + (lane & 15);
    int k0  = kt * 32 + (lane >> 4) * 8;
    const float* src = W + (size_t)row * KD + k0;
    f32x4 f0 = *reinterpret_cast<const f32x4*>(src);
    f32x4 f1 = *reinterpret_cast<const f32x4*>(src + 4);
    s16x8 v;
    v[0]=(short)f2bf(f0[0]); v[1]=(short)f2bf(f0[1]);
    v[2]=(short)f2bf(f0[2]); v[3]=(short)f2bf(f0[3]);
    v[4]=(short)f2bf(f1[0]); v[5]=(short)f2bf(f1[1]);
    v[6]=(short)f2bf(f1[2]); v[7]=(short)f2bf(f1[3]);
    *reinterpret_cast<s16x8*>(Wb2 + (size_t)i * 8) = v;
}

__global__ void aux_k(const float* __restrict__ gt, float* __restrict__ out) {
    size_t i = (size_t)blockIdx.x * 256 + threadIdx.x;
    if (i < (size_t)NG * HD) {
        int g = (int)(i / HD), c = (int)(i % HD);
        out[(size_t)g * SEQ * HD + c] = gt[c];           // [graph] token row
    } else {
        size_t m = i - (size_t)NG * HD;
        if (m < MASK_ELEMS) out[TOK_ELEMS + m] = 1.0f;   // mask = True -> 1.0f
    }
}

// ---------------- main fused gather-GEMM-scatter ----------------
// block = 256 threads (4 waves), 128 A-rows per block; wave w owns rows
// [w*32, w*32+32) as two 16-row fragments; A in registers (2x10 bf16x8).
// B fragments are loaded DIRECTLY from the fragment-ordered Wb2 (L2-hot,
// 1KB coalesced per load): no LDS staging, no barriers, no lgkm waits in
// the hot loop -- waves run free so VMEM-store, VMEM-load and MFMA pipes
// of drifting waves overlap (the serialization r5-r10 could not remove).
__global__ __launch_bounds__(256, 3)
void gemm_scatter(const float* __restrict__ x,  const float* __restrict__ ea,
                  const float* __restrict__ P,  const float* __restrict__ EV,
                  const float* __restrict__ EEv,const float* __restrict__ bias,
                  const int* __restrict__ eidx, const int* __restrict__ batch,
                  const u16* __restrict__ Wb2,  const int* __restrict__ nptr,
                  const int* __restrict__ eptr, float* __restrict__ out)
{
    __shared__ int info_src[128], info_pu[128], info_pv[128], info_orow[128];

    const int tid  = threadIdx.x;
    const int lane = tid & 63;
    const int wid  = tid >> 6;
    const int lrow = lane & 15;
    const int lq   = lane >> 4;

    const int r0  = blockIdx.x * 128;
    const bool isNode = (r0 < NN);     // NN % 128 == 0: uniform per block
    const float* feat = isNode ? x  : ea;
    const float* idv  = isNode ? EV : EEv;

    if (tid < 128) {
        int r = r0 + tid;
        if (isNode) {
            int g = batch[r];
            info_src[tid] = r; info_pu[tid] = r; info_pv[tid] = r;
            info_orow[tid] = g * SEQ + 1 + (r - nptr[g]);
        } else {
            int e = r - NN;
            int s = eidx[e], d = eidx[NE + e];
            int g = batch[s];
            info_src[tid] = e; info_pu[tid] = s; info_pv[tid] = d;
            info_orow[tid] = g * SEQ + 1 + NPG + (e - eptr[g]);
        }
    }
    __syncthreads();

    // ---- A fragments: gather + convert directly into registers ----
    bf16x8 afr[2][10];
    int obase[2][4];
    #pragma unroll
    for (int rb = 0; rb < 2; ++rb) {
        const int arow = wid * 32 + rb * 16 + lrow;
        const int fsrc = info_src[arow];
        const int pu   = info_pu[arow];
        const int pv   = info_pv[arow];
        #pragma unroll
        for (int s = 0; s < 10; ++s) {
            const int kg = s * 32 + lq * 8;   // 8-k slice, never straddles segments
            const float* sp;
            if      (s < 4) sp = feat + (size_t)fsrc * DN + kg;
            else if (s < 6) sp = P + (size_t)pu * DP + (kg - DN);
            else if (s < 8) sp = P + (size_t)pv * DP + (kg - DN - DP);
            else            sp = idv + (kg - DN - 2 * DP);
            f32x4 f0 = *reinterpret_cast<const f32x4*>(sp);
            f32x4 f1 = *reinterpret_cast<const f32x4*>(sp + 4);
            s16x8 v;
            v[0]=(short)f2bf(f0[0]); v[1]=(short)f2bf(f0[1]);
            v[2]=(short)f2bf(f0[2]); v[3]=(short)f2bf(f0[3]);
            v[4]=(short)f2bf(f1[0]); v[5]=(short)f2bf(f1[1]);
            v[6]=(short)f2bf(f1[2]); v[7]=(short)f2bf(f1[3]);
            afr[rb][s] = __builtin_bit_cast(bf16x8, v);
        }
        #pragma unroll
        for (int j = 0; j < 4; ++j)
            obase[rb][j] = info_orow[wid * 32 + rb * 16 + lq * 4 + j] * HD;
    }

    // per-lane fragment pointer (same for all waves -> L1/L2 broadcast)
    const char* pb = (const char*)Wb2 + (size_t)lane * 16;

    for (int nt = 0; nt < 12; ++nt) {
        const int n0 = nt * 64;
        const char* pnt = pb + (size_t)nt * 40960;   // 10*4*64*16 per nt
        f32x4 acc[2][4];
        #pragma unroll
        for (int rb = 0; rb < 2; ++rb)
            #pragma unroll
            for (int i = 0; i < 4; ++i) acc[rb][i] = (f32x4)0.f;

        #pragma unroll
        for (int kt = 0; kt < 10; ++kt) {
            bf16x8 b[4];
            #pragma unroll
            for (int ni = 0; ni < 4; ++ni)
                b[ni] = *reinterpret_cast<const bf16x8*>(pnt + kt * 4096 + ni * 1024);
            #pragma unroll
            for (int ni = 0; ni < 4; ++ni) {
                acc[0][ni] = __builtin_amdgcn_mfma_f32_16x16x32_bf16(afr[0][kt], b[ni], acc[0][ni], 0, 0, 0);
                acc[1][ni] = __builtin_amdgcn_mfma_f32_16x16x32_bf16(afr[1][kt], b[ni], acc[1][ni], 0, 0, 0);
            }
        }

        // ---- epilogue: bias + direct f32 scatter stores ----
        #pragma unroll
        for (int ni = 0; ni < 4; ++ni) {
            float bv = bias[n0 + ni * 16 + lrow];
            #pragma unroll
            for (int rb = 0; rb < 2; ++rb)
                #pragma unroll
                for (int j = 0; j < 4; ++j)
                    out[(size_t)(obase[rb][j] + n0 + ni * 16 + lrow)] =
                        acc[rb][ni][j] + bv;
        }
    }
}

extern "C" void kernel_launch(void* const* d_in, const int* in_sizes, int n_in,
                              void* d_out, int out_size, void* d_ws, size_t ws_size,
                              hipStream_t stream) {
    const float* x    = (const float*)d_in[0];
    const float* ea   = (const float*)d_in[1];
    const float* P    = (const float*)d_in[2];
    const float* EV   = (const float*)d_in[3];
    const float* EEv  = (const float*)d_in[4];
    const float* W    = (const float*)d_in[5];
    const float* bias = (const float*)d_in[6];
    const float* gt   = (const float*)d_in[7];
    const int* eidx   = (const int*)d_in[8];
    const int* batch  = (const int*)d_in[9];

    float* out = (float*)d_out;
    u16* Wb2 = (u16*)d_ws;
    int* ints = (int*)((char*)d_ws + (size_t)KD * HD * 2);
    int *nptr = ints, *eptr = ints + 32;

    ptr_k<<<1, 64, 0, stream>>>(batch, eidx, nptr, eptr);
    wconv_k<<<(NFRAG + 255) / 256, 256, 0, stream>>>(W, Wb2);
    aux_k<<<(int)(((size_t)NG * HD + MASK_ELEMS + 255) / 256), 256, 0, stream>>>(gt, out);
    gemm_scatter<<<dim3((NN + NE) / 128), 256, 0, stream>>>(
        x, ea, P, EV, EEv, bias, eidx, batch, Wb2, nptr, eptr, out);
}

// Round 13
// 171.771 us; speedup vs baseline: 1.5274x; 1.5274x over previous
//
#include <hip/hip_runtime.h>
#include <stdint.h>

#define NG   32
#define NPG  512
#define EPG  4096
#define DN   128
#define DP   64
#define NN   (NG*NPG)          // 16384 nodes
#define NE   (NG*EPG)          // 131072 edges
#define KD   320               // in_dim
#define HD   768               // hidden
#define SEQ  (1+NPG+EPG)       // 4609
#define TOK_ELEMS ((size_t)NG*SEQ*HD)
#define MASK_ELEMS ((size_t)NG*SEQ)

typedef unsigned short u16;
typedef __attribute__((ext_vector_type(8))) __bf16 bf16x8;
typedef __attribute__((ext_vector_type(8))) short  s16x8;
typedef __attribute__((ext_vector_type(4))) float  f32x4;

__device__ __forceinline__ u16 f2bf(float f) {
    uint32_t u = __builtin_bit_cast(uint32_t, f);
    u += 0x7fffu + ((u >> 16) & 1u);          // RNE
    return (u16)(u >> 16);
}

// B-tile LDS layout (per 4KB K-subtile of 64 W-rows x 32 k bf16): rows
// pair-packed into 128B lines, 16B k-slots XOR-swizzled by row-pair bits ->
// wave64 b128 column-slice read covers all 32 banks evenly. Same formula on
// write and read side (both-sides-or-neither rule).
__device__ __forceinline__ int b_off(int row, int kb) {
    return ((row >> 1) << 7) + ((row & 1) << 6) + (kb ^ (((row >> 1) & 3) << 4));
}

// ---------------- aux kernels ----------------
__global__ void ptr_k(const int* __restrict__ batch, const int* __restrict__ eidx,
                      int* __restrict__ nptr, int* __restrict__ eptr) {
    int t = threadIdx.x;
    if (t < NG) {
        int g = t, lo = 0, hi = NN;
        while (lo < hi) { int mid = (lo + hi) >> 1; if (batch[mid] < g) lo = mid + 1; else hi = mid; }
        nptr[g] = lo;
    } else if (t < 2 * NG) {
        int g = t - NG, lo = 0, hi = NE;
        while (lo < hi) { int mid = (lo + hi) >> 1; if (batch[eidx[mid]] < g) lo = mid + 1; else hi = mid; }
        eptr[g] = lo;
    }
}

__global__ void wconv_k(const float* __restrict__ W, u16* __restrict__ Wb) {
    int i = blockIdx.x * 256 + threadIdx.x;
    if (i < KD * HD) Wb[i] = f2bf(W[i]);       // keep [H][K] row-major layout
}

__global__ void aux_k(const float* __restrict__ gt, float* __restrict__ out) {
    size_t i = (size_t)blockIdx.x * 256 + threadIdx.x;
    if (i < (size_t)NG * HD) {
        int g = (int)(i / HD), c = (int)(i % HD);
        out[(size_t)g * SEQ * HD + c] = gt[c];           // [graph] token row
    } else {
        size_t m = i - (size_t)NG * HD;
        if (m < MASK_ELEMS) out[TOK_ELEMS + m] = 1.0f;   // mask = True -> 1.0f
    }
}

// ---------------- main fused gather-GEMM-scatter ----------------
// r9 structure (169 us) with a register diet (collapsed staging maps:
// second unit = +20480 global / +2048 LDS immediate) and CORRECT r9 tile
// bookkeeping (r12's linear gp walk was wrong at 64-row panel boundaries).
// __launch_bounds__(256,3) targets 3 blocks/CU so the three co-resident
// blocks' store bursts overlap other blocks' LDS/MFMA phases.
__global__ __launch_bounds__(256, 3)
void gemm_scatter(const float* __restrict__ x,  const float* __restrict__ ea,
                  const float* __restrict__ P,  const float* __restrict__ EV,
                  const float* __restrict__ EEv,const float* __restrict__ bias,
                  const int* __restrict__ eidx, const int* __restrict__ batch,
                  const u16* __restrict__ Wb,   const int* __restrict__ nptr,
                  const int* __restrict__ eptr, float* __restrict__ out)
{
    __shared__ __align__(16) char b_lds[2][8192];    // 16 KB
    __shared__ int info_src[128], info_pu[128], info_pv[128], info_orow[128];

    const int tid  = threadIdx.x;
    const int lane = tid & 63;
    const int wid  = tid >> 6;
    const int lrow = lane & 15;
    const int lq   = lane >> 4;

    // ---- staging maps: unit u = tid covers row tid>>3 (<32), chunk tid&7;
    //      unit u+256 is row+32: +20480 B global, +2048 B LDS (b_off
    //      identity: (row+32)>>1 adds 16 lines = +2048, XOR bits unchanged).
    const uint32_t row0 = (uint32_t)tid >> 3, c0 = (uint32_t)tid & 7;
    const uint32_t g_off = row0 * (KD * 2) + c0 * 16;
    const uint32_t l_off = ((c0 >> 2) * 4096u) + (uint32_t)b_off((int)row0, (int)((c0 & 3) * 16));
    const char* WbB = (const char*)Wb;

    const int r0  = blockIdx.x * 128;
    const bool isNode = (r0 < NN);     // NN % 128 == 0: uniform per block
    const float* feat = isNode ? x  : ea;
    const float* idv  = isNode ? EV : EEv;

    if (tid < 128) {
        int r = r0 + tid;
        if (isNode) {
            int g = batch[r];
            info_src[tid] = r; info_pu[tid] = r; info_pv[tid] = r;
            info_orow[tid] = g * SEQ + 1 + (r - nptr[g]);
        } else {
            int e = r - NN;
            int s = eidx[e], d = eidx[NE + e];
            int g = batch[s];
            info_src[tid] = e; info_pu[tid] = s; info_pv[tid] = d;
            info_orow[tid] = g * SEQ + 1 + NPG + (e - eptr[g]);
        }
    }
    __syncthreads();

    // ---- A fragments: gather + convert directly into registers ----
    bf16x8 afr[2][10];
    int obase[2][4];
    #pragma unroll
    for (int rb = 0; rb < 2; ++rb) {
        const int arow = wid * 32 + rb * 16 + lrow;
        const int fsrc = info_src[arow];
        const int pu   = info_pu[arow];
        const int pv   = info_pv[arow];
        #pragma unroll
        for (int s = 0; s < 10; ++s) {
            const int kg = s * 32 + lq * 8;   // 8-k slice, never straddles segments
            const float* sp;
            if      (s < 4) sp = feat + (size_t)fsrc * DN + kg;
            else if (s < 6) sp = P + (size_t)pu * DP + (kg - DN);
            else if (s < 8) sp = P + (size_t)pv * DP + (kg - DN - DP);
            else            sp = idv + (kg - DN - 2 * DP);
            f32x4 f0 = *reinterpret_cast<const f32x4*>(sp);
            f32x4 f1 = *reinterpret_cast<const f32x4*>(sp + 4);
            s16x8 v;
            v[0]=(short)f2bf(f0[0]); v[1]=(short)f2bf(f0[1]);
            v[2]=(short)f2bf(f0[2]); v[3]=(short)f2bf(f0[3]);
            v[4]=(short)f2bf(f1[0]); v[5]=(short)f2bf(f1[1]);
            v[6]=(short)f2bf(f1[2]); v[7]=(short)f2bf(f1[3]);
            afr[rb][s] = __builtin_bit_cast(bf16x8, v);
        }
        #pragma unroll
        for (int j = 0; j < 4; ++j)
            obase[rb][j] = info_orow[wid * 32 + rb * 16 + lq * 4 + j] * HD;
    }

    const int roff = b_off(lrow, lq * 16);    // read-side swizzle, ni-invariant

    // prologue: stage tile 0 into registers
    s16x8 pre0 = *reinterpret_cast<const s16x8*>(WbB + g_off);
    s16x8 pre1 = *reinterpret_cast<const s16x8*>(WbB + g_off + 20480);

    int cur = 0;
    int nxt = 1;                       // next tile index (of 60)
    for (int nt = 0; nt < 12; ++nt) {
        const int n0 = nt * 64;
        f32x4 acc[2][4];
        #pragma unroll
        for (int rb = 0; rb < 2; ++rb)
            #pragma unroll
            for (int i = 0; i < 4; ++i) acc[rb][i] = (f32x4)0.f;

        #pragma unroll
        for (int kp = 0; kp < 5; ++kp) {
            cur ^= 1;
            char* bb = &b_lds[0][0] + cur * 8192;
            // write this phase's tile (staged one phase ago; vmem landed)
            *reinterpret_cast<s16x8*>(bb + l_off)        = pre0;
            *reinterpret_cast<s16x8*>(bb + l_off + 2048) = pre1;
            // issue next tile's loads (consumed next phase); tile tn lives at
            // panel ntn=tn/5 (64 rows x 640B) + k-offset kpn*128.
            {
                int tn  = (nxt < 60) ? nxt : 59; ++nxt;
                int ntn = tn / 5, kpn = tn - ntn * 5;
                const char* gb = WbB + (size_t)ntn * (64 * KD * 2) + kpn * 128;
                pre0 = *reinterpret_cast<const s16x8*>(gb + g_off);
                pre1 = *reinterpret_cast<const s16x8*>(gb + g_off + 20480);
            }
            asm volatile("s_waitcnt lgkmcnt(0)" ::: "memory");
            __builtin_amdgcn_sched_barrier(0);
            __builtin_amdgcn_s_barrier();
            #pragma unroll
            for (int kk = 0; kk < 2; ++kk) {
                const int kt = kp * 2 + kk;
                const char* bs = bb + kk * 4096;
                #pragma unroll
                for (int ni = 0; ni < 4; ++ni) {
                    bf16x8 bf = *reinterpret_cast<const bf16x8*>(bs + ni * 1024 + roff);
                    acc[0][ni] = __builtin_amdgcn_mfma_f32_16x16x32_bf16(afr[0][kt], bf, acc[0][ni], 0, 0, 0);
                    acc[1][ni] = __builtin_amdgcn_mfma_f32_16x16x32_bf16(afr[1][kt], bf, acc[1][ni], 0, 0, 0);
                }
            }
            // reads of bb finish before our next lgkmcnt(0)+barrier, which
            // precedes any write to this buffer two phases later.
        }

        // ---- epilogue: bias + direct f32 scatter stores ----
        #pragma unroll
        for (int ni = 0; ni < 4; ++ni) {
            float bv = bias[n0 + ni * 16 + lrow];
            #pragma unroll
            for (int rb = 0; rb < 2; ++rb)
                #pragma unroll
                for (int j = 0; j < 4; ++j)
                    out[(size_t)(obase[rb][j] + n0 + ni * 16 + lrow)] =
                        acc[rb][ni][j] + bv;
        }
    }
}

extern "C" void kernel_launch(void* const* d_in, const int* in_sizes, int n_in,
                              void* d_out, int out_size, void* d_ws, size_t ws_size,
                              hipStream_t stream) {
    const float* x    = (const float*)d_in[0];
    const float* ea   = (const float*)d_in[1];
    const float* P    = (const float*)d_in[2];
    const float* EV   = (const float*)d_in[3];
    const float* EEv  = (const float*)d_in[4];
    const float* W    = (const float*)d_in[5];
    const float* bias = (const float*)d_in[6];
    const float* gt   = (const float*)d_in[7];
    const int* eidx   = (const int*)d_in[8];
    const int* batch  = (const int*)d_in[9];

    float* out = (float*)d_out;
    u16* Wb  = (u16*)d_ws;
    int* ints = (int*)((char*)d_ws + (size_t)KD * HD * 2);
    int *nptr = ints, *eptr = ints + 32;

    ptr_k<<<1, 64, 0, stream>>>(batch, eidx, nptr, eptr);
    wconv_k<<<(KD * HD + 255) / 256, 256, 0, stream>>>(W, Wb);
    aux_k<<<(int)(((size_t)NG * HD + MASK_ELEMS + 255) / 256), 256, 0, stream>>>(gt, out);
    gemm_scatter<<<dim3((NN + NE) / 128), 256, 0, stream>>>(
        x, ea, P, EV, EEv, bias, eidx, batch, Wb, nptr, eptr, out);
}